// Round 11
// baseline (17902.219 us; speedup 1.0000x reference)
//
#include <hip/hip_runtime.h>
#include <math.h>

#define SLEN 8192
#define DIM  256
#define H2N  256
#define G4   1024
#define NTAG 16
#define NEGV (-10000.0f)

// ws layout (float offsets unless noted)
#define OFF_PRE_F   0
#define OFF_PRE_B   (SLEN*G4)
#define OFF_HS_F    (2*SLEN*G4)
#define OFF_HS_B    (2*SLEN*G4 + SLEN*H2N)
#define OFF_FEATS   (2*SLEN*G4 + 2*SLEN*H2N)
#define WS_NEEDED   ((size_t)(OFF_FEATS + SLEN*NTAG) * 4)

typedef unsigned int u32x4 __attribute__((ext_vector_type(4)));
typedef __fp16 h2_t __attribute__((ext_vector_type(2)));

__device__ __forceinline__ unsigned pack2(float x, float y) {
#if __has_builtin(__builtin_amdgcn_cvt_pkrtz)
    return __builtin_bit_cast(unsigned, __builtin_amdgcn_cvt_pkrtz(x, y));
#else
    union { __fp16 h[2]; unsigned u; } t;
    t.h[0] = (__fp16)x; t.h[1] = (__fp16)y;
    return t.u;
#endif
}

#if __has_builtin(__builtin_amdgcn_fdot2)
__device__ __forceinline__ float fdot2(unsigned a, unsigned b, float c) {
    return __builtin_amdgcn_fdot2(__builtin_bit_cast(h2_t, a),
                                  __builtin_bit_cast(h2_t, b), c, false);
}
#else
__device__ __forceinline__ float fdot2(unsigned a, unsigned b, float c) {
    union { unsigned u; __fp16 h[2]; } ua, ub;
    ua.u = a; ub.u = b;
    return c + (float)ua.h[0] * (float)ub.h[0] + (float)ua.h[1] * (float)ub.h[1];
}
#endif

// in-register reduce over the 8 k-group lanes (lane bits 0..2). All three
// DPP patterns are SYMMETRIC (involutions); verified end-to-end by R8-R10's
// absmax=5.0 passes (f16-rounding class — a reduction bug would be O(100+)):
//   0xB1 = quad_perm[1,0,3,2]  (lane ^ 1)
//   0x4E = quad_perm[2,3,0,1]  (lane ^ 2)
//   0x141 = ROW_HALF_MIRROR    (lane ^ 7 within each 8-lane half-row)
template <int CTRL>
__device__ __forceinline__ float dpp_add(float x) {
    int v = __builtin_amdgcn_update_dpp(0, __float_as_int(x), CTRL, 0xF, 0xF, true);
    return x + __int_as_float(v);
}

// ---------------- K1: pre = gather(emb, sentence[±]) @ w_ih^T + b ----------------
__global__ __launch_bounds__(256) void gemm_pre(
    const int* __restrict__ sent, const float* __restrict__ emb,
    const float* __restrict__ wf, const float* __restrict__ bf,
    const float* __restrict__ wb, const float* __restrict__ bb,
    float* __restrict__ pre_f, float* __restrict__ pre_b)
{
    const int dir = blockIdx.z;
    const float* w    = dir ? wb : wf;
    const float* bias = dir ? bb : bf;
    float* out        = dir ? pre_b : pre_f;
    const int m0 = blockIdx.x * 64, n0 = blockIdx.y * 64;

    __shared__ float As[16][68];   // [k][m], row stride 272 B (16B-aligned)
    __shared__ float Bs[16][68];   // [k][n]
    __shared__ int   sidx[64];

    const int tid = threadIdx.x;
    const int tx = tid & 15, ty = tid >> 4;

    if (tid < 64) {
        int m = m0 + tid;
        int pos = dir ? (SLEN - 1 - m) : m;
        sidx[tid] = sent[pos];
    }
    __syncthreads();

    float acc[4][4];
#pragma unroll
    for (int i = 0; i < 4; i++)
#pragma unroll
        for (int j = 0; j < 4; j++) acc[i][j] = 0.f;

    const int lr = tid >> 2, lc = (tid & 3) * 4;

    for (int k0 = 0; k0 < DIM; k0 += 16) {
        float4 av = *(const float4*)(emb + (size_t)sidx[lr] * DIM + k0 + lc);
        float4 bv = *(const float4*)(w + (size_t)(n0 + lr) * DIM + k0 + lc);
        As[lc+0][lr] = av.x; As[lc+1][lr] = av.y; As[lc+2][lr] = av.z; As[lc+3][lr] = av.w;
        Bs[lc+0][lr] = bv.x; Bs[lc+1][lr] = bv.y; Bs[lc+2][lr] = bv.z; Bs[lc+3][lr] = bv.w;
        __syncthreads();
#pragma unroll
        for (int k = 0; k < 16; k++) {
            float4 a4 = *(const float4*)&As[k][ty * 4];
            float4 b4 = *(const float4*)&Bs[k][tx * 4];
            float a[4] = {a4.x, a4.y, a4.z, a4.w};
            float b[4] = {b4.x, b4.y, b4.z, b4.w};
#pragma unroll
            for (int i = 0; i < 4; i++)
#pragma unroll
                for (int j = 0; j < 4; j++) acc[i][j] += a[i] * b[j];
        }
        __syncthreads();
    }

    float4 b4 = *(const float4*)(bias + n0 + tx*4);
#pragma unroll
    for (int i = 0; i < 4; i++) {
        float4 v;
        v.x = acc[i][0] + b4.x; v.y = acc[i][1] + b4.y;
        v.z = acc[i][2] + b4.z; v.w = acc[i][3] + b4.w;
        *(float4*)(out + (size_t)(m0 + ty*4 + i) * G4 + n0 + tx*4) = v;
    }
}

__device__ __forceinline__ float fast_sigmoid(float x) {
    return 1.f / (1.f + __expf(-x));
}
__device__ __forceinline__ float fast_tanh(float x) {
    float xc = fminf(fmaxf(x, -15.f), 15.f);
    float e = __expf(2.f * xc);
    return (e - 1.f) / (e + 1.f);
}

// ---------------- K2: ONE CU per direction — zero cross-block exchange ----------------
// R18 (= R17 + direct register-budget attribute):
// R9/R10 proved this toolchain IGNORES __launch_bounds__' 2nd argument:
// (512,2) and (512,1) both produced VGPR_Count=128 (inconsistent with both
// the waves-per-EU and blocks-per-CU interpretations). The 192-reg W array
// is therefore still spilling to scratch (~2500cy/step: the gap between the
// ~1800cy {VALU+LDS+barriers} model and the measured 4370cy period).
// Fix: the documented clang AMDGPU attributes, which feed the register
// allocator directly:
//   amdgpu_flat_work_group_size(512,512) + amdgpu_waves_per_eu(1,2)
// min-waves/EU=1 -> VGPR cap = min(pool/1, ArchVGPR ceiling) = 256. The
// 8-wave block at 256 regs = 2048 regs = the full CU pool = 1 block/CU,
// which is this kernel's actual residency (LDS 133KB forces it anyway).
// Everything else unchanged (verified: absmax=5.0 across R8-R10, LDS
// bank conflicts = 0 after R10's hbuf 80B-stride padding):
//  - W f16 512KB: rows 0..11 in 192 VGPRs, rows 12..15 in 128KB LDS.
//  - per row: 16 fdot2 (fp32 accum) + 3 symmetric DPP adds (0xB1/0x4E/
//    0x141) -> kg0 lane holds full gate-row sum.
//  - gsum [gate*256+cell]: conflict-free write (banks=slot%32) and read
//    (lane-consecutive).
//  - act threads<256: gates+pre, fp32 c-state, h->f16 hbuf (80B-stride
//    regions) + NT history; pre(t+1) prefetched.
__global__ __attribute__((amdgpu_flat_work_group_size(512, 512)))
__attribute__((amdgpu_waves_per_eu(1, 2)))
void lstm_kernel(
    const float* __restrict__ pre_f, const float* __restrict__ pre_b,
    const float* __restrict__ whh_f, const float* __restrict__ whh_b,
    const float* __restrict__ h0_f, const float* __restrict__ c0_f,
    const float* __restrict__ h0_b, const float* __restrict__ c0_b,
    float* __restrict__ hs_f, float* __restrict__ hs_b)
{
    const int d = blockIdx.x;            // 0..1: direction
    const float* pre = d ? pre_b : pre_f;
    const float* whh = d ? whh_b : whh_f;
    const float* h0  = d ? h0_b : h0_f;
    const float* c0  = d ? c0_b : c0_f;
    float* hs        = d ? hs_b : hs_f;

    const int tid = threadIdx.x;         // 0..511
    const int l   = tid & 63;
    const int w   = tid >> 6;            // wave 0..7
    const int kg  = l & 7;               // k-group (32 ks)
    const int rl  = l >> 3;              // row-lane 0..7
    const int slot = w * 8 + rl;         // 0..63
    const int k0 = kg * 32;

    __shared__ __align__(16) u32x4  wlds[16][512];  // 128 KB: rows 12..15
    __shared__ __align__(16) __fp16 hbuf[8 * 40];   // 640 B: 8 regions x 80 B
    __shared__ __align__(16) float  gsum[1024];     // 4 KB, [gate*256 + cell]

    // ---- stage W -> f16: rows 0..11 to VGPRs, 12..15 to LDS ----
    unsigned wreg[12][16];
#pragma unroll
    for (int i = 0; i < 16; i++) {
        const float* wsrc = whh + (size_t)(slot + 64 * i) * H2N + k0;
        unsigned pk[16];
#pragma unroll
        for (int q = 0; q < 8; q++) {
            float4 v = *(const float4*)(wsrc + 4 * q);
            pk[2 * q]     = pack2(v.x, v.y);
            pk[2 * q + 1] = pack2(v.z, v.w);
        }
        if (i < 12) {
#pragma unroll
            for (int p = 0; p < 16; p++) wreg[i][p] = pk[p];
        } else {
#pragma unroll
            for (int c4 = 0; c4 < 4; c4++) {
                u32x4 vv;
                vv.x = pk[4*c4+0]; vv.y = pk[4*c4+1];
                vv.z = pk[4*c4+2]; vv.w = pk[4*c4+3];
                wlds[(i - 12) * 4 + c4][tid] = vv;
            }
        }
    }

    // ---- init: h0 -> f16 region buffer, c-state + pre(0) in act regs ----
    float cst = 0.f, prg0 = 0.f, prg1 = 0.f, prg2 = 0.f, prg3 = 0.f;
    if (tid < 256) {
        // half index tid -> region tid>>5 (80B stride), elem tid&31
        *(__fp16*)((char*)hbuf + (tid >> 5) * 80 + (tid & 31) * 2) = (__fp16)h0[tid];
        cst  = c0[tid];
        prg0 = pre[0 * 256 + tid];
        prg1 = pre[1 * 256 + tid];
        prg2 = pre[2 * 256 + tid];
        prg3 = pre[3 * 256 + tid];
    }
    __syncthreads();

    for (int t = 0; t < SLEN; t++) {
        // ---- load h (broadcast, packed f16 pairs) into regs ----
        unsigned hreg[16];
        {
            const u32x4* hp = (const u32x4*)((const char*)hbuf + kg * 80);
#pragma unroll
            for (int j = 0; j < 4; j++) {
                u32x4 hv = hp[j];
                hreg[4*j+0] = hv.x; hreg[4*j+1] = hv.y;
                hreg[4*j+2] = hv.z; hreg[4*j+3] = hv.w;
            }
        }

        // ---- 16 gate-row partial dots + DPP reduce + gsum scatter ----
#pragma unroll
        for (int b = 0; b < 4; b++) {
            float sv[4];
#pragma unroll
            for (int ii = 0; ii < 4; ii++) {
                const int i = 4 * b + ii;
                float a0 = 0.f, a1 = 0.f;
                if (i < 12) {
#pragma unroll
                    for (int p = 0; p < 16; p += 2) {
                        a0 = fdot2(wreg[i][p],     hreg[p],     a0);
                        a1 = fdot2(wreg[i][p + 1], hreg[p + 1], a1);
                    }
                } else {
#pragma unroll
                    for (int c4 = 0; c4 < 4; c4++) {
                        u32x4 wc = wlds[(i - 12) * 4 + c4][tid];
                        a0 = fdot2(wc.x, hreg[4*c4+0], a0);
                        a1 = fdot2(wc.y, hreg[4*c4+1], a1);
                        a0 = fdot2(wc.z, hreg[4*c4+2], a0);
                        a1 = fdot2(wc.w, hreg[4*c4+3], a1);
                    }
                }
                float a = a0 + a1;
                a = dpp_add<0xB1>(a);    // + (kg^1)
                a = dpp_add<0x4E>(a);    // + (kg^2)
                a = dpp_add<0x141>(a);   // + (kg^7): other quad (half-mirror)
                sv[ii] = a;
            }
            if (kg == 0) {
                // gate b, cells slot+64*ii: banks = slot%32 -> the 8 kg0
                // lanes of a wave hit 8 distinct banks (conflict-free)
                gsum[b * 256 + slot +   0] = sv[0];
                gsum[b * 256 + slot +  64] = sv[1];
                gsum[b * 256 + slot + 128] = sv[2];
                gsum[b * 256 + slot + 192] = sv[3];
            }
        }
        __syncthreads();   // A: gate sums visible

        // ---- activations on threads 0..255 (cell = tid) ----
        if (tid < 256) {
            const int cc = tid;
            // lane-consecutive reads: conflict-free
            float s_i = gsum[  0 + cc] + prg0;
            float s_f = gsum[256 + cc] + prg1;
            float s_g = gsum[512 + cc] + prg2;
            float s_o = gsum[768 + cc] + prg3;
            float i_ = fast_sigmoid(s_i);
            float f_ = fast_sigmoid(s_f);
            float g_ = fast_tanh(s_g);
            float o_ = fast_sigmoid(s_o);
            cst = f_ * cst + i_ * g_;
            float h = o_ * fast_tanh(cst);
            __fp16 hh = (__fp16)h;
            *(__fp16*)((char*)hbuf + (cc >> 5) * 80 + (cc & 31) * 2) = hh;
            // history = the f16-rounded h actually used by the recurrence
            __builtin_nontemporal_store((float)hh, hs + (size_t)t * H2N + cc);
            // prefetch pre(t+1): lands during next step's dot phase
            if (t < SLEN - 1) {
                const float* pn = pre + (size_t)(t + 1) * G4 + cc;
                prg0 = pn[0];   prg1 = pn[256];
                prg2 = pn[512]; prg3 = pn[768];
            }
        }
        __syncthreads();   // B: h ready for next step
    }
}

// ---------------- K3: feats = concat(hs_f[s], hs_b[S-1-s]) @ w_out^T + b_out ----------------
__global__ __launch_bounds__(256) void feats_kernel(
    const float* __restrict__ hs_f, const float* __restrict__ hs_b,
    const float* __restrict__ w_out, const float* __restrict__ b_out,
    float* __restrict__ feats)
{
    const int rs0 = blockIdx.x * 16;
    const int tid = threadIdx.x;
    const int r = tid >> 4, cc = tid & 15;

    __shared__ float Hs[16][516];   // row stride 2064 B (16B-aligned)
    for (int i = tid; i < 16 * 256; i += 256) {
        int rr = i >> 8, k = i & 255;
        Hs[rr][k]       = hs_f[(size_t)(rs0 + rr) * H2N + k];
        Hs[rr][256 + k] = hs_b[(size_t)(SLEN - 1 - (rs0 + rr)) * H2N + k];
    }
    __syncthreads();

    float acc = 0.f;
    const float* wr = w_out + (size_t)cc * 512;
    const float* hrow = Hs[r];
#pragma unroll 4
    for (int kq = 0; kq < 128; kq++) {
        float4 hv = *(const float4*)(hrow + 4 * kq);
        float4 wv = *(const float4*)(wr + 4 * kq);
        acc += hv.x * wv.x; acc += hv.y * wv.y;
        acc += hv.z * wv.z; acc += hv.w * wv.w;
    }
    feats[(size_t)(rs0 + r) * NTAG + cc] = acc + b_out[cc];
}

// ---------------- K4: Viterbi scan + backtrack (single wave, LDS back-ptrs) ----------------
__global__ __launch_bounds__(64) void viterbi_kernel(
    const float* __restrict__ feats, const float* __restrict__ trans,
    float* __restrict__ out)
{
    __shared__ unsigned char back_s[SLEN * 8];   // 65536 B, [t][tag/2] nibbles

    const int lane = threadIdx.x;
    const int nx = lane >> 2, pc = lane & 3;   // next tag, prev-chunk

    float tr[4];
#pragma unroll
    for (int j = 0; j < 4; j++) tr[j] = trans[nx * NTAG + pc * 4 + j];

    // score of tag g lives (replicated) in lanes 4g..4g+3
    float sc = (nx == 0) ? 0.f : NEGV;
    float fe = feats[nx];   // prefetch t=0

    for (int t = 0; t < SLEN; t++) {
        float fe_next = (t < SLEN - 1) ? feats[(size_t)(t + 1) * NTAG + nx] : 0.f;

        float bv; int bi;
#pragma unroll
        for (int j = 0; j < 4; j++) {
            float s = __shfl(sc, 4 * (pc * 4 + j), 64);
            float cand = s + tr[j];
            if (j == 0) { bv = cand; bi = pc * 4; }
            else if (cand > bv) { bv = cand; bi = pc * 4 + j; }
        }
        // combine across the 4 prev-chunks; first-max semantics (tie -> smaller idx)
#pragma unroll
        for (int off = 1; off < 4; off <<= 1) {
            float ov = __shfl_xor(bv, off, 64);
            int   oi = __shfl_xor(bi, off, 64);
            if (ov > bv || (ov == bv && oi < bi)) { bv = ov; bi = oi; }
        }
        // nibble-pack: lane (nx even, pc==0) stores [bi(nx) | bi(nx+1)<<4]
        int bi_part = __shfl(bi, (nx | 1) * 4, 64);
        if (pc == 0 && (nx & 1) == 0)
            back_s[t * 8 + (nx >> 1)] = (unsigned char)((bi & 15) | (bi_part << 4));
        sc = bv + fe;
        fe = fe_next;
    }

    // final = last + trans[END=1]; first-argmax
    float bestv = 0.f; int besti = 0;
#pragma unroll
    for (int j = 0; j < NTAG; j++) {
        float sj = __shfl(sc, 4 * j, 64);
        float fj = sj + trans[1 * NTAG + j];
        if (j == 0) { bestv = fj; besti = 0; }
        else if (fj > bestv) { bestv = fj; besti = j; }
    }
    __syncthreads();

    if (lane == 0) {
        out[0] = bestv;
        int cur = besti;
        for (int t = SLEN - 1; t >= 1; t--) {
            out[1 + t] = (float)cur;
            unsigned char byte = back_s[t * 8 + (cur >> 1)];
            cur = (cur & 1) ? (byte >> 4) : (byte & 15);
        }
        out[1] = (float)cur;
    }
}

extern "C" void kernel_launch(void* const* d_in, const int* in_sizes, int n_in,
                              void* d_out, int out_size, void* d_ws, size_t ws_size,
                              hipStream_t stream) {
    const int*   sent   = (const int*)d_in[0];
    const float* emb    = (const float*)d_in[1];
    const float* w_ih_f = (const float*)d_in[2];
    const float* w_hh_f = (const float*)d_in[3];
    const float* b_f    = (const float*)d_in[4];
    const float* w_ih_b = (const float*)d_in[5];
    const float* w_hh_b = (const float*)d_in[6];
    const float* b_b    = (const float*)d_in[7];
    const float* h0_f   = (const float*)d_in[8];
    const float* c0_f   = (const float*)d_in[9];
    const float* h0_b   = (const float*)d_in[10];
    const float* c0_b   = (const float*)d_in[11];
    const float* w_out  = (const float*)d_in[12];
    const float* b_out  = (const float*)d_in[13];
    const float* trans  = (const float*)d_in[14];
    float* out = (float*)d_out;

    if (ws_size < WS_NEEDED) return;  // visible failure, no OOB writes

    float* ws = (float*)d_ws;
    float* pre_f = ws + OFF_PRE_F;
    float* pre_b = ws + OFF_PRE_B;
    float* hs_f  = ws + OFF_HS_F;
    float* hs_b  = ws + OFF_HS_B;
    float* feats = ws + OFF_FEATS;

    gemm_pre<<<dim3(128, 16, 2), 256, 0, stream>>>(sent, emb, w_ih_f, b_f, w_ih_b, b_b, pre_f, pre_b);
    lstm_kernel<<<2, 512, 0, stream>>>(pre_f, pre_b, w_hh_f, w_hh_b,
                                       h0_f, c0_f, h0_b, c0_b, hs_f, hs_b);
    feats_kernel<<<512, 256, 0, stream>>>(hs_f, hs_b, w_out, b_out, feats);
    viterbi_kernel<<<1, 64, 0, stream>>>(feats, trans, out);
}